// Round 8
// baseline (260.445 us; speedup 1.0000x reference)
//
#include <hip/hip_runtime.h>

// Performer (FAVOR+) attention, MI355X bf16-MFMA implementation.
// Round 8: RF-folding restructure. phi = relu((x@W)@RF) = relu(x@(W@RF)) —
// fold RF into W_q/W_k once (fold_w), so the qkv GEMM directly emits
// phi_q (row-major, relu) and phi_k / V (TRANSPOSED [bh][r|d][n], relu on k).
// kv = phi_k^T V becomes a pure linear-staged NT MFMA kernel (kv_gemm, ones
// row for k_sum); phiq_out drops RF/phi work to a single 20-MFMA pass.
// GEMM K-loop kept exactly as R7 (1 barrier + vmcnt(0) per K-tile, best so far).

typedef __attribute__((ext_vector_type(8))) short s8v;   // 8 x bf16 (4 VGPR)
typedef __attribute__((ext_vector_type(4))) short s4v;   // 4 x bf16
typedef __attribute__((ext_vector_type(4))) float f4v;   // MFMA acc
typedef __attribute__((ext_vector_type(4))) int   i4v;   // 16B chunk

#define MFMA16(a, b, c) __builtin_amdgcn_mfma_f32_16x16x32_bf16((a), (b), (c), 0, 0, 0)

__device__ __forceinline__ unsigned short f2bf(float f) {
  unsigned int u = __builtin_bit_cast(unsigned int, f);
  unsigned int r = (u + 0x7FFFu + ((u >> 16) & 1u)) >> 16;  // RNE
  return (unsigned short)r;
}

__device__ __forceinline__ int swz(int p) {   // 128B-row swizzle: bits 7..9 -> 4..6
  return p ^ (((p >> 7) & 7) << 4);
}
__device__ __forceinline__ int swz8(int p) {  // 256B-row swizzle: bits 8..10 -> 4..6
  return p ^ (((p >> 8) & 7) << 4);
}

__device__ __forceinline__ void gl_lds16(const void* g, void* l) {
  __builtin_amdgcn_global_load_lds(
      (const __attribute__((address_space(1))) void*)g,
      (__attribute__((address_space(3))) void*)l, 16, 0, 0);
}

// ---------------------------------------------------------------- prep
__global__ __launch_bounds__(256) void cvt_bf16(const float* __restrict__ in,
                                                unsigned short* __restrict__ out,
                                                int n4) {
  int i = blockIdx.x * 256 + threadIdx.x;
  if (i >= n4) return;
  f4v v = ((const f4v*)in)[i];
  s4v o;
#pragma unroll
  for (int j = 0; j < 4; ++j) o[j] = (short)f2bf(v[j]);
  ((s4v*)out)[i] = o;
}

// out[c][r] = bf16(in[r][c]); R,C multiples of 32. block (32,8)
__global__ __launch_bounds__(256) void transpose_cvt(const float* __restrict__ in,
                                                     unsigned short* __restrict__ out,
                                                     int R, int C) {
  __shared__ float tile[32][33];
  const int tx = threadIdx.x, ty = threadIdx.y;
  const int c0 = blockIdx.x * 32, r0 = blockIdx.y * 32;
#pragma unroll
  for (int j = 0; j < 4; ++j)
    tile[ty + j * 8][tx] = in[(size_t)(r0 + ty + j * 8) * C + c0 + tx];
  __syncthreads();
#pragma unroll
  for (int j = 0; j < 4; ++j)
    out[(size_t)(c0 + ty + j * 8) * R + r0 + tx] = f2bf(tile[tx][ty + j * 8]);
}

// ---------------------------------------------------------------- fold RF
// wqkvt[part*1024 + h*64 + r][k] = bf16( sum_d W_qkv[k][part*1024+h*64+d] * RF[h][d][r] )
// Overwrites rows 0..2047 of wqkvt (V rows 2048..3071 stay from transpose_cvt).
// grid (kc 0..7, h 0..15, part 0..1), 256 threads.
__global__ __launch_bounds__(256) void fold_w(const float* __restrict__ W_qkv,
                                              const float* __restrict__ RF,
                                              unsigned short* __restrict__ wqkvt) {
  __shared__ float RFl[64 * 64];    // [d][r]
  __shared__ float Wl[128 * 65];    // [kk][d] (+pad: lanes read kk-strided)
  const int t = threadIdx.x;
  const int k0 = blockIdx.x * 128, h = blockIdx.y, part = blockIdx.z;
#pragma unroll
  for (int i = 0; i < 16; ++i) RFl[i * 256 + t] = RF[h * 4096 + i * 256 + t];
#pragma unroll
  for (int i = 0; i < 32; ++i) {
    int idx = i * 256 + t, kk = idx >> 6, d = idx & 63;
    Wl[kk * 65 + d] = W_qkv[(size_t)(k0 + kk) * 3072 + part * 1024 + h * 64 + d];
  }
  __syncthreads();
  const int w = t >> 6, lane = t & 63;
  const int rg = w >> 1;                 // r group (0/1)
  const int kk = (w & 1) * 64 + lane;    // 0..127, lanes consecutive
#pragma unroll
  for (int j = 0; j < 32; ++j) {
    const int r = rg * 32 + j;           // wave-uniform
    float s = 0.f;
#pragma unroll
    for (int d = 0; d < 64; ++d) s += Wl[kk * 65 + d] * RFl[d * 64 + r];
    wqkvt[(size_t)(part * 1024 + h * 64 + r) * 1024 + k0 + kk] = f2bf(s);
  }
}

// ---------------------------------------------------------------- GEMM 256x256
// C = A[M,K] @ Bt[N,K]^T.  R7 loop (1 barrier + vmcnt(0)/K-tile), 8 waves,
// LDS swizzle p^=((p>>7)&7)<<4 (inverse-swizzled global src + swizzled read).
// MODE 0 (qkv): tn 0-3 -> phi_q row-major [16384][1024] w/ relu;
//               tn 4-7 -> kT[bh][r][4096] transposed, relu, packed 8B;
//               tn 8-11 -> vT[bh][d][4096] transposed, packed 8B.
// MODE 1: f32 + bias row-major (final out GEMM).
template <int MODE>
__global__ __launch_bounds__(512, 2) void gemm256(const unsigned short* __restrict__ A,
                                                  const unsigned short* __restrict__ Bt,
                                                  void* __restrict__ Cout,
                                                  unsigned short* __restrict__ kT,
                                                  unsigned short* __restrict__ vT,
                                                  const float* __restrict__ bias,
                                                  int Nn, int K, int NTN, int CPX) {
  __shared__ __align__(128) unsigned short smem[65536];  // 128 KiB
  const int t = threadIdx.x, w = t >> 6, lane = t & 63;
  const int wm = w >> 2, wn = w & 3;
  const int fr = lane & 15, c16 = (lane >> 4) * 16;
  const int nkt = K >> 6;

  const int bid = blockIdx.x;
  const int wg = (bid & 7) * CPX + (bid >> 3);
  const int tm = wg / NTN, tn = wg % NTN;

  const unsigned short* gA = A + (size_t)tm * 256 * K;
  const unsigned short* gB = Bt + (size_t)tn * 256 * K;

  const int s0 = swz(t * 16);
  const int s1 = swz(8192 + t * 16);
  const int goff0 = (s0 >> 7) * K + ((s0 & 127) >> 1);
  const int goff1 = ((s1 - 8192) >> 7) * K + ((s1 & 127) >> 1) + 64 * K;
  const int woff = w * 1024;

  auto stage = [&](int T2, int part) {
    if (T2 >= nkt) return;
    char* reg = (char*)smem + (((T2 & 1) * 4 + part) << 14);
    const unsigned short* gp =
        (part < 2 ? gA : gB) + (size_t)((part & 1) * 128) * K + T2 * 64;
    gl_lds16(gp + goff0, reg + woff);
    gl_lds16(gp + goff1, reg + 8192 + woff);
  };

  f4v acc[8][4] = {};
  stage(0, 0); stage(0, 1); stage(0, 2); stage(0, 3);

  auto rdA = [&](int mh, s8v (&a)[4][2], const char* Ar) {
#pragma unroll
    for (int i = 0; i < 4; ++i)
#pragma unroll
      for (int ks = 0; ks < 2; ++ks) {
        int p = swz((mh * 64 + i * 16 + fr) * 128 + ks * 64 + c16);
        a[i][ks] = *(const s8v*)(Ar + p);
      }
  };
  auto rdB = [&](int nh, s8v (&b)[2][2], const char* Br, int brow) {
#pragma unroll
    for (int j = 0; j < 2; ++j)
#pragma unroll
      for (int ks = 0; ks < 2; ++ks) {
        int p = swz((brow + nh * 32 + j * 16 + fr) * 128 + ks * 64 + c16);
        b[j][ks] = *(const s8v*)(Br + p);
      }
  };
  auto mmac = [&](int mh, int nh, const s8v (&a)[4][2], const s8v (&b)[2][2]) {
    __builtin_amdgcn_s_setprio(1);
#pragma unroll
    for (int i = 0; i < 4; ++i)
#pragma unroll
      for (int j = 0; j < 2; ++j) {
        acc[mh * 4 + i][nh * 2 + j] = MFMA16(a[i][0], b[j][0], acc[mh * 4 + i][nh * 2 + j]);
        acc[mh * 4 + i][nh * 2 + j] = MFMA16(a[i][1], b[j][1], acc[mh * 4 + i][nh * 2 + j]);
      }
    __builtin_amdgcn_s_setprio(0);
  };

  const int brow = (wn & 1) * 64;
  for (int T = 0; T < nkt; ++T) {
    const int d = T & 1;
    const char* Ar = (const char*)smem + ((d * 4 + wm) << 14);
    const char* Br = (const char*)smem + ((d * 4 + 2 + (wn >> 1)) << 14);
    asm volatile("s_waitcnt vmcnt(0)" ::: "memory");
    __builtin_amdgcn_s_barrier();
    __builtin_amdgcn_sched_barrier(0);
    stage(T + 1, 0); stage(T + 1, 1); stage(T + 1, 2); stage(T + 1, 3);
    s8v a[4][2], b0[2][2], b1[2][2];
    rdA(0, a, Ar); rdB(0, b0, Br, brow); rdB(1, b1, Br, brow);
    mmac(0, 0, a, b0);
    mmac(0, 1, a, b1);
    rdA(1, a, Ar);
    mmac(1, 1, a, b1);
    mmac(1, 0, a, b0);
  }

  // epilogue
  const int sec = tn >> 2;  // MODE 0: 0=phi_q, 1=kT, 2=vT
#pragma unroll
  for (int m = 0; m < 8; ++m)
#pragma unroll
    for (int n = 0; n < 4; ++n) {
      const int row = tm * 256 + wm * 128 + m * 16 + (lane >> 4) * 4;
      const int col = tn * 256 + wn * 64 + n * 16 + fr;
      if (MODE == 0) {
        if (sec == 0) {
          unsigned short* C = (unsigned short*)Cout;  // phi_q [16384][1024]
#pragma unroll
          for (int r = 0; r < 4; ++r)
            C[(size_t)(row + r) * 1024 + col] = f2bf(fmaxf(acc[m][n][r], 0.0f));
        } else {
          const int cl = col & 1023;
          const int bh = (row >> 12) * 16 + (cl >> 6);
          unsigned short* T = (sec == 1) ? kT : vT;
          s4v o;
#pragma unroll
          for (int g = 0; g < 4; ++g)
            o[g] = (short)f2bf(sec == 1 ? fmaxf(acc[m][n][g], 0.0f) : acc[m][n][g]);
          *(s4v*)&T[((size_t)bh * 64 + (cl & 63)) * 4096 + (row & 4095)] = o;
        }
      } else {
        float* C = (float*)Cout;
        const float bv = bias[col];
#pragma unroll
        for (int r = 0; r < 4; ++r)
          C[(size_t)(row + r) * Nn + col] = acc[m][n][r] + bv;
      }
    }
}

// ---------------------------------------------------------------- kv GEMM
// kvpart[bh][och][d'][r] += sum_n kT[bh][r][n] * vS[d'][n], d'=64 is ones row
// (k_sum). block = (och 0..7, bh 0..63): 512 tokens in 4 slices of 128.
// LDS per buf: kS[64][128] (16KB) + vS[80][128] (20KB); dbuf = 72KB.
// 256B rows -> swz8 swizzle (inverse-swizzled global src + swizzled read).
__global__ __launch_bounds__(256) void kv_gemm(const unsigned short* __restrict__ kT,
                                               const unsigned short* __restrict__ vT,
                                               float* __restrict__ kvpart) {
  __shared__ __align__(128) char lds[2 * 36864];
  const int t = threadIdx.x, w = t >> 6, lane = t & 63;
  const int och = blockIdx.x, bh = blockIdx.y;
  const int fr = lane & 15, c16 = (lane >> 4) * 16;
  const char* kTb = (const char*)kT + (size_t)bh * 64 * 8192 + och * 1024;
  const char* vTb = (const char*)vT + (size_t)bh * 64 * 8192 + och * 1024;

  // static vS rows 64..79 (ones / zeros) in both buffers, at swizzled spots
  for (int i = t; i < 2 * 2048; i += 256) {
    int buf = i >> 11, e = i & 2047;          // e over 16 rows x 128 cols
    int row = 64 + (e >> 7), c = e & 127;
    int p = swz8(row * 256 + c * 2);
    *(unsigned short*)&lds[buf * 36864 + 16384 + p] = (row == 64) ? 0x3F80 : 0;
  }

  // per-thread inverse-swizzled source offsets for staging (4 units each mat)
  int srcoff[4];
#pragma unroll
  for (int i = 0; i < 4; ++i) {
    int p = swz8((i * 256 + t) * 16);
    srcoff[i] = (p >> 8) * 8192 + (p & 255);
  }
  auto stage = [&](int s) {
    if (s >= 4) return;
    char* base = lds + (s & 1) * 36864;
#pragma unroll
    for (int i = 0; i < 4; ++i) {
      gl_lds16(kTb + s * 256 + srcoff[i], base + (i * 256 + w * 64) * 16);
      gl_lds16(vTb + s * 256 + srcoff[i], base + 16384 + (i * 256 + w * 64) * 16);
    }
  };

  f4v kvacc[5] = {};
  stage(0);
  for (int s = 0; s < 4; ++s) {
    asm volatile("s_waitcnt vmcnt(0)" ::: "memory");
    __builtin_amdgcn_s_barrier();
    __builtin_amdgcn_sched_barrier(0);
    stage(s + 1);
    const char* kB = lds + (s & 1) * 36864;
    const char* vB = kB + 16384;
    s8v a[4];
#pragma unroll
    for (int ks = 0; ks < 4; ++ks)
      a[ks] = *(const s8v*)(kB + swz8((w * 16 + fr) * 256 + ks * 64 + c16));
    __builtin_amdgcn_s_setprio(1);
#pragma unroll
    for (int f = 0; f < 5; ++f) {
#pragma unroll
      for (int ks = 0; ks < 4; ++ks) {
        s8v b = *(const s8v*)(vB + swz8((f * 16 + fr) * 256 + ks * 64 + c16));
        kvacc[f] = MFMA16(a[ks], b, kvacc[f]);
      }
    }
    __builtin_amdgcn_s_setprio(0);
  }
  // D: row ~ kT rows (r = w*16 + (lane>>4)*4 + g), col ~ vS rows (d' = f*16+fr)
  float* outp = kvpart + ((size_t)bh * 8 + och) * (80 * 64);
#pragma unroll
  for (int f = 0; f < 5; ++f)
    *(f4v*)&outp[(f * 16 + fr) * 64 + w * 16 + (lane >> 4) * 4] = kvacc[f];
}

__global__ __launch_bounds__(256) void kv_reduce(const float* __restrict__ kvpart,
                                                 unsigned short* __restrict__ kvt) {
  const int bh = blockIdx.x, t = threadIdx.x;
  for (int i = t; i < 80 * 64; i += 256) {
    float s = 0.f;
#pragma unroll
    for (int c = 0; c < 8; ++c) s += kvpart[((size_t)bh * 8 + c) * 5120 + i];
    kvt[(size_t)bh * 5120 + i] = f2bf(s);
  }
}

// ---------------------------------------------------------------- phi_q @ kv
// block = (ch 0..31, h, b); 128 tokens. attno[n][h*64+d] = (phi_q@kv)/(phi_q.k_sum+eps)
__global__ __launch_bounds__(256) void phiq_out(const unsigned short* __restrict__ phiq,
                                                const unsigned short* __restrict__ kvt,
                                                unsigned short* __restrict__ attno) {
  __shared__ __align__(128) unsigned short phl[128 * 64];  // [n][r], swz
  __shared__ unsigned short kvl[80 * 72];                  // [d'][r] (+pad), 64=k_sum
  const int t = threadIdx.x, w = t >> 6, lane = t & 63;
  const int ch = blockIdx.x, h = blockIdx.y, b = blockIdx.z;
  const int fr = lane & 15, kg = (lane >> 4) * 8, c16 = (lane >> 4) * 16;
  const int bh = b * 16 + h;
  const size_t rowbase = (size_t)(b * 4096 + ch * 128);
  const char* src = (const char*)phiq + rowbase * 2048 + h * 128;

#pragma unroll
  for (int i = 0; i < 4; ++i) {  // stage phi_q [128][64] with swz
    int p = swz((i * 256 + t) * 16);
    gl_lds16(src + (p >> 7) * 2048 + (p & 127),
             (char*)phl + (i * 256 + w * 64) * 16);
  }
  for (int i = t; i < 640; i += 256) {  // kvt -> kvl (pad 64->72)
    int row = i >> 3, cg = (i & 7) * 8;
    *(i4v*)&kvl[row * 72 + cg] = *(const i4v*)&kvt[(size_t)bh * 5120 + row * 64 + cg];
  }
  __syncthreads();

  f4v acc[2][5] = {};
#pragma unroll
  for (int ks = 0; ks < 2; ++ks) {
    s8v pa[2], kb[5];
#pragma unroll
    for (int m = 0; m < 2; ++m)
      pa[m] = *(const s8v*)((const char*)phl +
                            swz((w * 32 + m * 16 + fr) * 128 + ks * 64 + c16));
#pragma unroll
    for (int f = 0; f < 5; ++f)
      kb[f] = *(const s8v*)&kvl[(f * 16 + fr) * 72 + ks * 32 + kg];
#pragma unroll
    for (int m = 0; m < 2; ++m)
#pragma unroll
      for (int f = 0; f < 5; ++f) acc[m][f] = MFMA16(pa[m], kb[f], acc[m][f]);
  }
#pragma unroll
  for (int m = 0; m < 2; ++m)
#pragma unroll
    for (int g = 0; g < 4; ++g) {
      float nrm = __shfl(acc[m][4][g], lane & 48) + 1e-6f;  // col 64 = phi_q.k_sum
      int n = w * 32 + m * 16 + (lane >> 4) * 4 + g;
      size_t orow = rowbase + n;
#pragma unroll
      for (int f = 0; f < 4; ++f)
        attno[orow * 1024 + h * 64 + f * 16 + fr] = f2bf(acc[m][f][g] / nrm);
    }
}

// ---------------------------------------------------------------- launch
extern "C" void kernel_launch(void* const* d_in, const int* in_sizes, int n_in,
                              void* d_out, int out_size, void* d_ws, size_t ws_size,
                              hipStream_t stream) {
  const float* x = (const float*)d_in[0];      // [4,4096,1024]
  const float* W_qkv = (const float*)d_in[1];  // [1024,3072]
  const float* RF = (const float*)d_in[2];     // [16,64,64]
  const float* W_out = (const float*)d_in[3];  // [1024,1024]
  const float* b_out = (const float*)d_in[4];  // [1024]
  float* out = (float*)d_out;                  // [4,4096,1024]

  char* ws = (char*)d_ws;
  size_t off = 0;
  auto alloc = [&](size_t bytes) -> void* {
    void* p = ws + off;
    off += (bytes + 255) & ~(size_t)255;
    return p;
  };
  unsigned short* xb = (unsigned short*)alloc(16384ull * 1024 * 2);
  unsigned short* wqkvt = (unsigned short*)alloc(3072ull * 1024 * 2);
  unsigned short* woutt = (unsigned short*)alloc(1024ull * 1024 * 2);
  unsigned short* phiq = (unsigned short*)alloc(16384ull * 1024 * 2);
  unsigned short* kT = (unsigned short*)alloc(64ull * 64 * 4096 * 2);
  unsigned short* vT = (unsigned short*)alloc(64ull * 64 * 4096 * 2);
  float* kvpart = (float*)alloc(64ull * 8 * 80 * 64 * 4);
  unsigned short* kvt = (unsigned short*)alloc(64ull * 80 * 64 * 2);
  unsigned short* attno = (unsigned short*)alloc(16384ull * 1024 * 2);

  cvt_bf16<<<16384, 256, 0, stream>>>(x, xb, 4194304);
  transpose_cvt<<<dim3(96, 32), dim3(32, 8), 0, stream>>>(W_qkv, wqkvt, 1024, 3072);
  transpose_cvt<<<dim3(32, 32), dim3(32, 8), 0, stream>>>(W_out, woutt, 1024, 1024);
  fold_w<<<dim3(8, 16, 2), 256, 0, stream>>>(W_qkv, RF, wqkvt);

  // phi_q / kT / vT : M=16384 x N=3072 (12 tiles), grid 768
  gemm256<0><<<768, 512, 0, stream>>>(xb, wqkvt, phiq, kT, vT, nullptr,
                                      3072, 1024, 12, 96);
  kv_gemm<<<dim3(8, 64), 256, 0, stream>>>(kT, vT, kvpart);
  kv_reduce<<<64, 256, 0, stream>>>(kvpart, kvt);
  phiq_out<<<dim3(32, 16, 4), 256, 0, stream>>>(phiq, kvt, attno);
  // out = attno @ woutt^T + b : M=16384 x N=1024 (4 tiles), grid 256
  gemm256<1><<<256, 512, 0, stream>>>(attno, woutt, out, nullptr, nullptr, b_out,
                                      1024, 1024, 4, 32);
}

// Round 9
// 256.903 us; speedup vs baseline: 1.0138x; 1.0138x over previous
//
#include <hip/hip_runtime.h>

// Performer (FAVOR+) attention, MI355X bf16-MFMA implementation.
// Round 9: RF-folding kept (phi = relu(x@(W@RF))), but the big GEMM writes
// ONE row-major [16384][3072] buffer {phi_q|phi_k|v} with R7's exact
// coalesced epilogue (R8's transposed stores caused 25MB write amplification
// and +14us on the GEMM). Transposes happen in phik_kv's LDS (proven R7
// pattern). kT/vT/kv_gemm removed. GEMM K-loop = R7 (best known: 106us).

typedef __attribute__((ext_vector_type(8))) short s8v;   // 8 x bf16 (4 VGPR)
typedef __attribute__((ext_vector_type(4))) short s4v;   // 4 x bf16
typedef __attribute__((ext_vector_type(4))) float f4v;   // MFMA acc
typedef __attribute__((ext_vector_type(4))) int   i4v;   // 16B chunk

#define MFMA16(a, b, c) __builtin_amdgcn_mfma_f32_16x16x32_bf16((a), (b), (c), 0, 0, 0)

__device__ __forceinline__ unsigned short f2bf(float f) {
  unsigned int u = __builtin_bit_cast(unsigned int, f);
  unsigned int r = (u + 0x7FFFu + ((u >> 16) & 1u)) >> 16;  // RNE
  return (unsigned short)r;
}

__device__ __forceinline__ int swz(int p) {   // 128B-row swizzle: bits 7..9 -> 4..6
  return p ^ (((p >> 7) & 7) << 4);
}

__device__ __forceinline__ void gl_lds16(const void* g, void* l) {
  __builtin_amdgcn_global_load_lds(
      (const __attribute__((address_space(1))) void*)g,
      (__attribute__((address_space(3))) void*)l, 16, 0, 0);
}

// ---------------------------------------------------------------- prep
__global__ __launch_bounds__(256) void cvt_bf16(const float* __restrict__ in,
                                                unsigned short* __restrict__ out,
                                                int n4) {
  int i = blockIdx.x * 256 + threadIdx.x;
  if (i >= n4) return;
  f4v v = ((const f4v*)in)[i];
  s4v o;
#pragma unroll
  for (int j = 0; j < 4; ++j) o[j] = (short)f2bf(v[j]);
  ((s4v*)out)[i] = o;
}

// out[c][r] = bf16(in[r][c]); R,C(stride) mult of 32. block (32,8)
__global__ __launch_bounds__(256) void transpose_cvt(const float* __restrict__ in,
                                                     unsigned short* __restrict__ out,
                                                     int R, int C) {
  __shared__ float tile[32][33];
  const int tx = threadIdx.x, ty = threadIdx.y;
  const int c0 = blockIdx.x * 32, r0 = blockIdx.y * 32;
#pragma unroll
  for (int j = 0; j < 4; ++j)
    tile[ty + j * 8][tx] = in[(size_t)(r0 + ty + j * 8) * C + c0 + tx];
  __syncthreads();
#pragma unroll
  for (int j = 0; j < 4; ++j)
    out[(size_t)(c0 + ty + j * 8) * R + r0 + tx] = f2bf(tile[tx][ty + j * 8]);
}

// ---------------------------------------------------------------- fold RF
// wqkvt[part*1024 + h*64 + r][k] = bf16( sum_d W_qkv[k][part*1024+h*64+d] * RF[h][d][r] )
// grid (kc 0..7, h 0..15, part 0..1), 256 threads.
__global__ __launch_bounds__(256) void fold_w(const float* __restrict__ W_qkv,
                                              const float* __restrict__ RF,
                                              unsigned short* __restrict__ wqkvt) {
  __shared__ float RFl[64 * 64];    // [d][r]
  __shared__ float Wl[128 * 65];    // [kk][d] (+pad)
  const int t = threadIdx.x;
  const int k0 = blockIdx.x * 128, h = blockIdx.y, part = blockIdx.z;
#pragma unroll
  for (int i = 0; i < 16; ++i) RFl[i * 256 + t] = RF[h * 4096 + i * 256 + t];
#pragma unroll
  for (int i = 0; i < 32; ++i) {
    int idx = i * 256 + t, kk = idx >> 6, d = idx & 63;
    Wl[kk * 65 + d] = W_qkv[(size_t)(k0 + kk) * 3072 + part * 1024 + h * 64 + d];
  }
  __syncthreads();
  const int w = t >> 6, lane = t & 63;
  const int rg = w >> 1;
  const int kk = (w & 1) * 64 + lane;
#pragma unroll
  for (int j = 0; j < 32; ++j) {
    const int r = rg * 32 + j;
    float s = 0.f;
#pragma unroll
    for (int d = 0; d < 64; ++d) s += Wl[kk * 65 + d] * RFl[d * 64 + r];
    wqkvt[(size_t)(part * 1024 + h * 64 + r) * 1024 + k0 + kk] = f2bf(s);
  }
}

// ---------------------------------------------------------------- GEMM 256x256
// C = A[M,K] @ Bt[N,K]^T.  R7 loop (1 barrier + vmcnt(0)/K-tile), 8 waves,
// LDS swizzle p^=((p>>7)&7)<<4 (inverse-swizzled global src + swizzled read).
// MODE 0: bf16 row-major out, relu for col<2048 (phi_q|phi_k|v layout).
// MODE 1: f32 + bias row-major.
template <int MODE>
__global__ __launch_bounds__(512, 2) void gemm256(const unsigned short* __restrict__ A,
                                                  const unsigned short* __restrict__ Bt,
                                                  void* __restrict__ Cout,
                                                  const float* __restrict__ bias,
                                                  int Nn, int K, int NTN, int CPX) {
  __shared__ __align__(128) unsigned short smem[65536];  // 128 KiB
  const int t = threadIdx.x, w = t >> 6, lane = t & 63;
  const int wm = w >> 2, wn = w & 3;
  const int fr = lane & 15, c16 = (lane >> 4) * 16;
  const int nkt = K >> 6;

  const int bid = blockIdx.x;
  const int wg = (bid & 7) * CPX + (bid >> 3);
  const int tm = wg / NTN, tn = wg % NTN;

  const unsigned short* gA = A + (size_t)tm * 256 * K;
  const unsigned short* gB = Bt + (size_t)tn * 256 * K;

  const int s0 = swz(t * 16);
  const int s1 = swz(8192 + t * 16);
  const int goff0 = (s0 >> 7) * K + ((s0 & 127) >> 1);
  const int goff1 = ((s1 - 8192) >> 7) * K + ((s1 & 127) >> 1) + 64 * K;
  const int woff = w * 1024;

  auto stage = [&](int T2, int part) {
    if (T2 >= nkt) return;
    char* reg = (char*)smem + (((T2 & 1) * 4 + part) << 14);
    const unsigned short* gp =
        (part < 2 ? gA : gB) + (size_t)((part & 1) * 128) * K + T2 * 64;
    gl_lds16(gp + goff0, reg + woff);
    gl_lds16(gp + goff1, reg + 8192 + woff);
  };

  f4v acc[8][4] = {};
  stage(0, 0); stage(0, 1); stage(0, 2); stage(0, 3);

  auto rdA = [&](int mh, s8v (&a)[4][2], const char* Ar) {
#pragma unroll
    for (int i = 0; i < 4; ++i)
#pragma unroll
      for (int ks = 0; ks < 2; ++ks) {
        int p = swz((mh * 64 + i * 16 + fr) * 128 + ks * 64 + c16);
        a[i][ks] = *(const s8v*)(Ar + p);
      }
  };
  auto rdB = [&](int nh, s8v (&b)[2][2], const char* Br, int brow) {
#pragma unroll
    for (int j = 0; j < 2; ++j)
#pragma unroll
      for (int ks = 0; ks < 2; ++ks) {
        int p = swz((brow + nh * 32 + j * 16 + fr) * 128 + ks * 64 + c16);
        b[j][ks] = *(const s8v*)(Br + p);
      }
  };
  auto mmac = [&](int mh, int nh, const s8v (&a)[4][2], const s8v (&b)[2][2]) {
    __builtin_amdgcn_s_setprio(1);
#pragma unroll
    for (int i = 0; i < 4; ++i)
#pragma unroll
      for (int j = 0; j < 2; ++j) {
        acc[mh * 4 + i][nh * 2 + j] = MFMA16(a[i][0], b[j][0], acc[mh * 4 + i][nh * 2 + j]);
        acc[mh * 4 + i][nh * 2 + j] = MFMA16(a[i][1], b[j][1], acc[mh * 4 + i][nh * 2 + j]);
      }
    __builtin_amdgcn_s_setprio(0);
  };

  const int brow = (wn & 1) * 64;
  for (int T = 0; T < nkt; ++T) {
    const int d = T & 1;
    const char* Ar = (const char*)smem + ((d * 4 + wm) << 14);
    const char* Br = (const char*)smem + ((d * 4 + 2 + (wn >> 1)) << 14);
    asm volatile("s_waitcnt vmcnt(0)" ::: "memory");
    __builtin_amdgcn_s_barrier();
    __builtin_amdgcn_sched_barrier(0);
    stage(T + 1, 0); stage(T + 1, 1); stage(T + 1, 2); stage(T + 1, 3);
    s8v a[4][2], b0[2][2], b1[2][2];
    rdA(0, a, Ar); rdB(0, b0, Br, brow); rdB(1, b1, Br, brow);
    mmac(0, 0, a, b0);
    mmac(0, 1, a, b1);
    rdA(1, a, Ar);
    mmac(1, 1, a, b1);
    mmac(1, 0, a, b0);
  }

  // epilogue: R7 row-major coalesced stores
  const bool rel = (MODE == 0) && (tn < 8);  // phi_q / phi_k columns get relu
#pragma unroll
  for (int m = 0; m < 8; ++m)
#pragma unroll
    for (int n = 0; n < 4; ++n) {
      const int row = tm * 256 + wm * 128 + m * 16 + (lane >> 4) * 4;
      const int col = tn * 256 + wn * 64 + n * 16 + fr;
      if (MODE == 0) {
        unsigned short* C = (unsigned short*)Cout;
#pragma unroll
        for (int r = 0; r < 4; ++r) {
          float v = acc[m][n][r];
          C[(size_t)(row + r) * Nn + col] = f2bf(rel ? fmaxf(v, 0.0f) : v);
        }
      } else {
        float* C = (float*)Cout;
        const float bv = bias[col];
#pragma unroll
        for (int r = 0; r < 4; ++r)
          C[(size_t)(row + r) * Nn + col] = acc[m][n][r] + bv;
      }
    }
}

// ---------------------------------------------------------------- phi_k^T v
// block = (och 0..7, h, b); 512 tokens in 4 chunks of 128.
// kvpart[bh][och][80][64]: rows 0..63 = kv^T (d',r), row 64 = k_sum, 65..79=0.
__global__ __launch_bounds__(256) void phik_kv(const unsigned short* __restrict__ phib,
                                               float* __restrict__ kvpart) {
  __shared__ unsigned short pkt[64 * 136];      // [r][n] (+pad)
  __shared__ unsigned short vt[80 * 136];       // [d][n] (+ones row 64)
  const int t = threadIdx.x, w = t >> 6, lane = t & 63;
  const int och = blockIdx.x, h = blockIdx.y, b = blockIdx.z;
  const int fr = lane & 15, kg = (lane >> 4) * 8;

  for (int i = t; i < 136; i += 256) vt[64 * 136 + i] = 0x3F80;     // ones row
  for (int i = t; i < 15 * 136; i += 256) vt[65 * 136 + i] = 0;     // zero pad

  f4v kvacc[5] = {};
  for (int c = 0; c < 4; ++c) {
    const size_t rowbase = (size_t)(b * 4096 + och * 512 + c * 128);
    i4v kreg[4], vreg[4];
#pragma unroll
    for (int it = 0; it < 4; ++it) {  // phi_k & v slices -> regs
      int slot = it * 256 + t;
      const unsigned short* rp =
          &phib[(rowbase + (slot >> 3)) * 3072 + h * 64 + (slot & 7) * 8];
      kreg[it] = *(const i4v*)(rp + 1024);
      vreg[it] = *(const i4v*)(rp + 2048);
    }
    __syncthreads();  // prev chunk's MFMA reads done before overwrite
#pragma unroll
    for (int it = 0; it < 4; ++it) {  // scalar transpose to LDS
      int slot = it * 256 + t;
      int vn = slot >> 3, c8 = (slot & 7) * 8;
      const unsigned short* kr = (const unsigned short*)&kreg[it];
      const unsigned short* vr = (const unsigned short*)&vreg[it];
#pragma unroll
      for (int j = 0; j < 8; ++j) {
        pkt[(c8 + j) * 136 + vn] = kr[j];
        vt[(c8 + j) * 136 + vn] = vr[j];
      }
    }
    __syncthreads();
    // kv_aug[d'][r] += vt @ pkt^T (wave w owns r-cols w*16..+15)
#pragma unroll
    for (int kst = 0; kst < 4; ++kst) {
      s8v pb = *(const s8v*)&pkt[(w * 16 + fr) * 136 + kst * 32 + kg];
#pragma unroll
      for (int f = 0; f < 5; ++f) {
        s8v va = *(const s8v*)&vt[(f * 16 + fr) * 136 + kst * 32 + kg];
        kvacc[f] = MFMA16(va, pb, kvacc[f]);
      }
    }
  }
  const int bh = b * 16 + h;
  float* outp = kvpart + ((size_t)bh * 8 + och) * (80 * 64);
#pragma unroll
  for (int f = 0; f < 5; ++f) {
    int row = f * 16 + (lane >> 4) * 4;
    int col = w * 16 + fr;
#pragma unroll
    for (int g = 0; g < 4; ++g) outp[(row + g) * 64 + col] = kvacc[f][g];
  }
}

__global__ __launch_bounds__(256) void kv_reduce(const float* __restrict__ kvpart,
                                                 unsigned short* __restrict__ kvt) {
  const int bh = blockIdx.x, t = threadIdx.x;
  for (int i = t; i < 80 * 64; i += 256) {
    float s = 0.f;
#pragma unroll
    for (int c = 0; c < 8; ++c) s += kvpart[((size_t)bh * 8 + c) * 5120 + i];
    kvt[(size_t)bh * 5120 + i] = f2bf(s);
  }
}

// ---------------------------------------------------------------- phi_q @ kv
// block = (ch 0..31, h, b); 128 tokens. attno[n][h*64+d] = (phi_q@kv)/(phi_q.k_sum+eps)
__global__ __launch_bounds__(256) void phiq_out(const unsigned short* __restrict__ phib,
                                                const unsigned short* __restrict__ kvt,
                                                unsigned short* __restrict__ attno) {
  __shared__ __align__(128) unsigned short phl[128 * 64];  // [n][r], swz
  __shared__ unsigned short kvl[80 * 72];                  // [d'][r] (+pad), 64=k_sum
  const int t = threadIdx.x, w = t >> 6, lane = t & 63;
  const int ch = blockIdx.x, h = blockIdx.y, b = blockIdx.z;
  const int fr = lane & 15, kg = (lane >> 4) * 8, c16 = (lane >> 4) * 16;
  const int bh = b * 16 + h;
  const size_t rowbase = (size_t)(b * 4096 + ch * 128);
  const char* src = (const char*)phib + rowbase * 6144 + h * 128;  // phi_q cols

#pragma unroll
  for (int i = 0; i < 4; ++i) {  // stage phi_q [128][64] with swz
    int p = swz((i * 256 + t) * 16);
    gl_lds16(src + (p >> 7) * 6144 + (p & 127),
             (char*)phl + (i * 256 + w * 64) * 16);
  }
  for (int i = t; i < 640; i += 256) {  // kvt -> kvl (pad 64->72)
    int row = i >> 3, cg = (i & 7) * 8;
    *(i4v*)&kvl[row * 72 + cg] = *(const i4v*)&kvt[(size_t)bh * 5120 + row * 64 + cg];
  }
  __syncthreads();

  f4v acc[2][5] = {};
#pragma unroll
  for (int ks = 0; ks < 2; ++ks) {
    s8v pa[2], kb[5];
#pragma unroll
    for (int m = 0; m < 2; ++m)
      pa[m] = *(const s8v*)((const char*)phl +
                            swz((w * 32 + m * 16 + fr) * 128 + ks * 64 + c16));
#pragma unroll
    for (int f = 0; f < 5; ++f)
      kb[f] = *(const s8v*)&kvl[(f * 16 + fr) * 72 + ks * 32 + kg];
#pragma unroll
    for (int m = 0; m < 2; ++m)
#pragma unroll
      for (int f = 0; f < 5; ++f) acc[m][f] = MFMA16(pa[m], kb[f], acc[m][f]);
  }
#pragma unroll
  for (int m = 0; m < 2; ++m)
#pragma unroll
    for (int g = 0; g < 4; ++g) {
      float nrm = __shfl(acc[m][4][g], lane & 48) + 1e-6f;  // col 64 = phi_q.k_sum
      int n = w * 32 + m * 16 + (lane >> 4) * 4 + g;
      size_t orow = rowbase + n;
#pragma unroll
      for (int f = 0; f < 4; ++f)
        attno[orow * 1024 + h * 64 + f * 16 + fr] = f2bf(acc[m][f][g] / nrm);
    }
}

// ---------------------------------------------------------------- launch
extern "C" void kernel_launch(void* const* d_in, const int* in_sizes, int n_in,
                              void* d_out, int out_size, void* d_ws, size_t ws_size,
                              hipStream_t stream) {
  const float* x = (const float*)d_in[0];      // [4,4096,1024]
  const float* W_qkv = (const float*)d_in[1];  // [1024,3072]
  const float* RF = (const float*)d_in[2];     // [16,64,64]
  const float* W_out = (const float*)d_in[3];  // [1024,1024]
  const float* b_out = (const float*)d_in[4];  // [1024]
  float* out = (float*)d_out;                  // [4,4096,1024]

  char* ws = (char*)d_ws;
  size_t off = 0;
  auto alloc = [&](size_t bytes) -> void* {
    void* p = ws + off;
    off += (bytes + 255) & ~(size_t)255;
    return p;
  };
  unsigned short* xb = (unsigned short*)alloc(16384ull * 1024 * 2);
  unsigned short* wqkvt = (unsigned short*)alloc(3072ull * 1024 * 2);
  unsigned short* woutt = (unsigned short*)alloc(1024ull * 1024 * 2);
  unsigned short* phib = (unsigned short*)alloc(16384ull * 3072 * 2);
  float* kvpart = (float*)alloc(64ull * 8 * 80 * 64 * 4);
  unsigned short* kvt = (unsigned short*)alloc(64ull * 80 * 64 * 2);
  unsigned short* attno = (unsigned short*)alloc(16384ull * 1024 * 2);

  cvt_bf16<<<16384, 256, 0, stream>>>(x, xb, 4194304);
  // only V-columns of W_qkv need the plain transpose (fold_w writes the rest)
  transpose_cvt<<<dim3(32, 32), dim3(32, 8), 0, stream>>>(
      W_qkv + 2048, wqkvt + 2048ull * 1024, 1024, 3072);
  transpose_cvt<<<dim3(32, 32), dim3(32, 8), 0, stream>>>(W_out, woutt, 1024, 1024);
  fold_w<<<dim3(8, 16, 2), 256, 0, stream>>>(W_qkv, RF, wqkvt);

  // {phi_q|phi_k|v} = relu-mix(xb @ wqkvt^T) : M=16384 x N=3072, grid 768
  gemm256<0><<<768, 512, 0, stream>>>(xb, wqkvt, phib, nullptr, 3072, 1024, 12, 96);
  phik_kv<<<dim3(8, 16, 4), 256, 0, stream>>>(phib, kvpart);
  kv_reduce<<<64, 256, 0, stream>>>(kvpart, kvt);
  phiq_out<<<dim3(32, 16, 4), 256, 0, stream>>>(phib, kvt, attno);
  // out = attno @ woutt^T + b : M=16384 x N=1024, grid 256
  gemm256<1><<<256, 512, 0, stream>>>(attno, woutt, out, b_out, 1024, 1024, 4, 32);
}

// Round 10
// 217.690 us; speedup vs baseline: 1.1964x; 1.1801x over previous
//
#include <hip/hip_runtime.h>

// Performer (FAVOR+) attention, MI355X bf16-MFMA implementation.
// Round 10: R7 verbatim (best known: 225us, qkv GEMM 106us @ ~972 TF) with
// the 4 independent prep kernels (cvt_bf16 + 3 transpose_cvt) merged into ONE
// prep_all dispatch (block-range branching) to cut graph-replay gaps: 9 -> 6
// dispatches. R8/R9's RF-folding reverted (fold_w + restructured mid-kernels
// cost more than the ~10us of work it removed; measured +32us).

typedef __attribute__((ext_vector_type(8))) short s8v;   // 8 x bf16 (4 VGPR)
typedef __attribute__((ext_vector_type(4))) short s4v;   // 4 x bf16
typedef __attribute__((ext_vector_type(4))) float f4v;   // MFMA acc
typedef __attribute__((ext_vector_type(4))) int   i4v;   // 16B chunk

#define MFMA16(a, b, c) __builtin_amdgcn_mfma_f32_16x16x32_bf16((a), (b), (c), 0, 0, 0)

__device__ __forceinline__ unsigned short f2bf(float f) {
  unsigned int u = __builtin_bit_cast(unsigned int, f);
  unsigned int r = (u + 0x7FFFu + ((u >> 16) & 1u)) >> 16;  // RNE
  return (unsigned short)r;
}

__device__ __forceinline__ int swz(int p) {          // involution, bits 7..9 -> 4..6
  return p ^ (((p >> 7) & 7) << 4);
}

__device__ __forceinline__ void gl_lds16(const void* g, void* l) {
  __builtin_amdgcn_global_load_lds(
      (const __attribute__((address_space(1))) void*)g,
      (__attribute__((address_space(3))) void*)l, 16, 0, 0);
}

// ---------------------------------------------------------------- prep (fused)
// blocks [0,16384): x f32 -> xb bf16 (f4v per thread).
// blocks [16384,19456): W_qkv [1024][3072] -> wqkvt [3072][1024] (T + cvt)
// blocks [19456,20480): W_out [1024][1024] -> woutt [1024][1024] (T + cvt)
// blocks [20480,20544): RF[h] [64][64] -> rft[h] [64][64] (T + cvt), h=idx>>2
__global__ __launch_bounds__(256) void prep_all(const float* __restrict__ x,
                                                unsigned short* __restrict__ xb,
                                                const float* __restrict__ W_qkv,
                                                unsigned short* __restrict__ wqkvt,
                                                const float* __restrict__ W_out,
                                                unsigned short* __restrict__ woutt,
                                                const float* __restrict__ RF,
                                                unsigned short* __restrict__ rft) {
  const int b = blockIdx.x, t = threadIdx.x;
  __shared__ float tile[32][33];
  if (b < 16384) {  // cvt path
    int i = b * 256 + t;
    f4v v = ((const f4v*)x)[i];
    s4v o;
#pragma unroll
    for (int j = 0; j < 4; ++j) o[j] = (short)f2bf(v[j]);
    ((s4v*)xb)[i] = o;
    return;
  }
  const float* in;
  unsigned short* out;
  int R, C, bx, by;
  if (b < 19456) {
    int idx = b - 16384;
    in = W_qkv; out = wqkvt; R = 1024; C = 3072; bx = idx % 96; by = idx / 96;
  } else if (b < 20480) {
    int idx = b - 19456;
    in = W_out; out = woutt; R = 1024; C = 1024; bx = idx & 31; by = idx >> 5;
  } else {
    int idx = b - 20480;
    in = RF + (idx >> 2) * 4096; out = rft + (idx >> 2) * 4096;
    R = 64; C = 64; bx = idx & 1; by = (idx >> 1) & 1;
  }
  const int tx = t & 31, ty = t >> 5;
  const int c0 = bx * 32, r0 = by * 32;
#pragma unroll
  for (int j = 0; j < 4; ++j)
    tile[ty + j * 8][tx] = in[(size_t)(r0 + ty + j * 8) * C + c0 + tx];
  __syncthreads();
#pragma unroll
  for (int j = 0; j < 4; ++j)
    out[(size_t)(c0 + ty + j * 8) * R + r0 + tx] = f2bf(tile[tx][ty + j * 8]);
}

// ---------------------------------------------------------------- GEMM 256x256
// C[M,N] = A[M,K] @ Bt[N,K]^T.  BK=64, 512 threads (8 waves, 2Mx4N),
// 128 KiB LDS = 2 dbuf x {A,B} x 2 halves x [128 rows][64 cols] bf16.
// LDS swizzle p ^= ((p>>7)&7)<<4 as inverse-swizzled global source + swizzled
// ds_read (rule 21). One barrier + one vmcnt(0) per K-tile: waves free-run
// the tile body; WAR-safe because every ds_read is consumed by an MFMA before
// the wave's next barrier arrival (R7 analysis).
template <int MODE>
__global__ __launch_bounds__(512, 2) void gemm256(const unsigned short* __restrict__ A,
                                                  const unsigned short* __restrict__ Bt,
                                                  void* __restrict__ Cout,
                                                  const float* __restrict__ bias,
                                                  int Nn, int K, int NTN, int CPX) {
  __shared__ __align__(128) unsigned short smem[65536];  // 128 KiB
  const int t = threadIdx.x, w = t >> 6, lane = t & 63;
  const int wm = w >> 2, wn = w & 3;
  const int fr = lane & 15, c16 = (lane >> 4) * 16;
  const int nkt = K >> 6;

  // T1: XCD-bijective block swizzle (grid % 8 == 0)
  const int bid = blockIdx.x;
  const int wg = (bid & 7) * CPX + (bid >> 3);
  const int tm = wg / NTN, tn = wg % NTN;

  const unsigned short* gA = A + (size_t)tm * 256 * K;
  const unsigned short* gB = Bt + (size_t)tn * 256 * K;

  // per-thread pre-swizzled global source offsets for the 2 staging loads
  const int s0 = swz(t * 16);
  const int s1 = swz(8192 + t * 16);
  const int goff0 = (s0 >> 7) * K + ((s0 & 127) >> 1);
  const int goff1 = ((s1 - 8192) >> 7) * K + ((s1 & 127) >> 1) + 64 * K;
  const int woff = w * 1024;  // wave-uniform LDS byte offset

  // parts: 0=A rows 0-127, 1=A rows 128-255, 2=B rows 0-127, 3=B rows 128-255
  auto stage = [&](int T2, int part) {
    if (T2 >= nkt) return;
    char* reg = (char*)smem + (((T2 & 1) * 4 + part) << 14);
    const unsigned short* gp =
        (part < 2 ? gA : gB) + (size_t)((part & 1) * 128) * K + T2 * 64;
    gl_lds16(gp + goff0, reg + woff);
    gl_lds16(gp + goff1, reg + 8192 + woff);
  };

  f4v acc[8][4] = {};

  // prologue: tile0 (8 loads); waited at top of T=0 (one-time exposed latency)
  stage(0, 0); stage(0, 1); stage(0, 2); stage(0, 3);

  auto rdA = [&](int mh, s8v (&a)[4][2], const char* Ar) {
#pragma unroll
    for (int i = 0; i < 4; ++i)
#pragma unroll
      for (int ks = 0; ks < 2; ++ks) {
        int p = swz((mh * 64 + i * 16 + fr) * 128 + ks * 64 + c16);
        a[i][ks] = *(const s8v*)(Ar + p);
      }
  };
  auto rdB = [&](int nh, s8v (&b)[2][2], const char* Br, int brow) {
#pragma unroll
    for (int j = 0; j < 2; ++j)
#pragma unroll
      for (int ks = 0; ks < 2; ++ks) {
        int p = swz((brow + nh * 32 + j * 16 + fr) * 128 + ks * 64 + c16);
        b[j][ks] = *(const s8v*)(Br + p);
      }
  };
  auto mmac = [&](int mh, int nh, const s8v (&a)[4][2], const s8v (&b)[2][2]) {
    __builtin_amdgcn_s_setprio(1);
#pragma unroll
    for (int i = 0; i < 4; ++i)
#pragma unroll
      for (int j = 0; j < 2; ++j) {
        acc[mh * 4 + i][nh * 2 + j] = MFMA16(a[i][0], b[j][0], acc[mh * 4 + i][nh * 2 + j]);
        acc[mh * 4 + i][nh * 2 + j] = MFMA16(a[i][1], b[j][1], acc[mh * 4 + i][nh * 2 + j]);
      }
    __builtin_amdgcn_s_setprio(0);
  };

  const int brow = (wn & 1) * 64;
  for (int T = 0; T < nkt; ++T) {
    const int d = T & 1;
    const char* Ar = (const char*)smem + ((d * 4 + wm) << 14);
    const char* Br = (const char*)smem + ((d * 4 + 2 + (wn >> 1)) << 14);
    // tile-top: my loads for tile T landed -> barrier -> everyone's landed.
    asm volatile("s_waitcnt vmcnt(0)" ::: "memory");
    __builtin_amdgcn_s_barrier();
    __builtin_amdgcn_sched_barrier(0);
    // prefetch tile T+1 into buffer d^1 (WAR-safe: d^1's reads drained
    // before every wave's arrival at the barrier above)
    stage(T + 1, 0); stage(T + 1, 1); stage(T + 1, 2); stage(T + 1, 3);
    s8v a[4][2], b0[2][2], b1[2][2];
    rdA(0, a, Ar); rdB(0, b0, Br, brow); rdB(1, b1, Br, brow);
    mmac(0, 0, a, b0);
    mmac(0, 1, a, b1);
    rdA(1, a, Ar);
    mmac(1, 1, a, b1);
    mmac(1, 0, a, b0);
  }

  // epilogue (row <-> a, col <-> b)
#pragma unroll
  for (int m = 0; m < 8; ++m)
#pragma unroll
    for (int n = 0; n < 4; ++n) {
      const int row = tm * 256 + wm * 128 + m * 16 + (lane >> 4) * 4;
      const int col = tn * 256 + wn * 64 + n * 16 + fr;
      if (MODE == 0) {
        unsigned short* C = (unsigned short*)Cout;
#pragma unroll
        for (int r = 0; r < 4; ++r)
          C[(size_t)(row + r) * Nn + col] = f2bf(acc[m][n][r]);
      } else {
        float* C = (float*)Cout;
        const float bv = bias[col];
#pragma unroll
        for (int r = 0; r < 4; ++r)
          C[(size_t)(row + r) * Nn + col] = acc[m][n][r] + bv;
      }
    }
}

// ---------------------------------------------------------------- phi_k + kv
// block = (och, h, b); processes 512 tokens in 4 chunks of 128.
// kvpart[bh][och][80][64]: rows 0..63 = kv^T (d,r), row 64 = k_sum, 65..79 = 0.
__global__ __launch_bounds__(256) void phik_kv(const unsigned short* __restrict__ qkv,
                                               const unsigned short* __restrict__ RFt,
                                               float* __restrict__ kvpart) {
  __shared__ unsigned short RFl[2 * 64 * 32];   // [p][r][32]
  __shared__ unsigned short Kl[2 * 128 * 32];   // [p][n][32]
  __shared__ unsigned short pht[64 * 136];      // [r][n] (+pad)
  __shared__ unsigned short vt[80 * 136];       // [d][n] (+ones row 64)
  const int t = threadIdx.x, w = t >> 6, lane = t & 63;
  const int och = blockIdx.x, h = blockIdx.y, b = blockIdx.z;
  const int fr = lane & 15, kg = (lane >> 4) * 8;

#pragma unroll
  for (int i = 0; i < 2; ++i) {  // RF[h] -> RFl
    int unit = i * 256 + w * 64 + lane;
    int p = unit >> 8, rem = unit & 255;
    int r = rem >> 2, cg = (rem & 3) * 8;
    gl_lds16(RFt + ((h * 64 + r) * 64 + p * 32 + cg), &RFl[(i * 256 + w * 64) * 8]);
  }
  for (int i = t; i < 136; i += 256) vt[64 * 136 + i] = 0x3F80;     // ones row
  for (int i = t; i < 15 * 136; i += 256) vt[65 * 136 + i] = 0;     // zero pad rows

  f4v kvacc[5] = {};

  for (int c = 0; c < 4; ++c) {
    const int n0c = och * 512 + c * 128;
    const size_t rowbase = (size_t)(b * 4096 + n0c);
#pragma unroll
    for (int i = 0; i < 4; ++i) {  // K slice -> Kl
      int unit = i * 256 + w * 64 + lane;
      int p = unit >> 9, rem = unit & 511;
      int n = rem >> 2, cg = (rem & 3) * 8;
      gl_lds16(qkv + (rowbase + n) * 3072 + 1024 + h * 64 + p * 32 + cg,
               &Kl[(i * 256 + w * 64) * 8]);
    }
    i4v vreg[4];
#pragma unroll
    for (int it = 0; it < 4; ++it) {  // V slice -> regs
      int slot = it * 256 + t;
      vreg[it] = *(const i4v*)&qkv[(rowbase + (slot >> 3)) * 3072 + 2048 + h * 64 +
                                   (slot & 7) * 8];
    }
    __syncthreads();
    // phi_k = relu(K @ RF)
    f4v pacc[2][4] = {};
#pragma unroll
    for (int p = 0; p < 2; ++p) {
      s8v ka[2], rb[4];
#pragma unroll
      for (int m = 0; m < 2; ++m)
        ka[m] = *(const s8v*)&Kl[p * 4096 + (w * 32 + m * 16 + fr) * 32 + kg];
#pragma unroll
      for (int rf = 0; rf < 4; ++rf)
        rb[rf] = *(const s8v*)&RFl[p * 2048 + (rf * 16 + fr) * 32 + kg];
#pragma unroll
      for (int m = 0; m < 2; ++m)
#pragma unroll
        for (int rf = 0; rf < 4; ++rf)
          pacc[m][rf] = MFMA16(ka[m], rb[rf], pacc[m][rf]);
    }
    // v -> vt (transposed)
#pragma unroll
    for (int it = 0; it < 4; ++it) {
      int slot = it * 256 + t;
      int vn = slot >> 3, vdh = (slot & 7) * 8;
      const unsigned short* vr = (const unsigned short*)&vreg[it];
#pragma unroll
      for (int j = 0; j < 8; ++j) vt[(vdh + j) * 136 + vn] = vr[j];
    }
    // phi -> pht (transposed, relu, bf16)
#pragma unroll
    for (int m = 0; m < 2; ++m)
#pragma unroll
      for (int rf = 0; rf < 4; ++rf) {
        int r = rf * 16 + fr;
        int nb = w * 32 + m * 16 + (lane >> 4) * 4;
        s4v pk;
#pragma unroll
        for (int g = 0; g < 4; ++g) pk[g] = (short)f2bf(fmaxf(pacc[m][rf][g], 0.0f));
        *(s4v*)&pht[r * 136 + nb] = pk;
      }
    __syncthreads();
    // kv_aug[d][r] += vt @ pht^T  (wave w owns r-cols w*16..+15)
#pragma unroll
    for (int kst = 0; kst < 4; ++kst) {
      s8v pb = *(const s8v*)&pht[(w * 16 + fr) * 136 + kst * 32 + kg];
#pragma unroll
      for (int f = 0; f < 5; ++f) {
        s8v va = *(const s8v*)&vt[(f * 16 + fr) * 136 + kst * 32 + kg];
        kvacc[f] = MFMA16(va, pb, kvacc[f]);
      }
    }
  }
  const int bh = b * 16 + h;
  float* outp = kvpart + ((size_t)bh * 8 + och) * (80 * 64);
#pragma unroll
  for (int f = 0; f < 5; ++f) {
    int row = f * 16 + (lane >> 4) * 4;
    int col = w * 16 + fr;
#pragma unroll
    for (int g = 0; g < 4; ++g) outp[(row + g) * 64 + col] = kvacc[f][g];
  }
}

__global__ __launch_bounds__(256) void kv_reduce(const float* __restrict__ kvpart,
                                                 unsigned short* __restrict__ kvt) {
  const int bh = blockIdx.x, t = threadIdx.x;
  for (int i = t; i < 80 * 64; i += 256) {
    float s = 0.f;
#pragma unroll
    for (int c = 0; c < 8; ++c) s += kvpart[((size_t)bh * 8 + c) * 5120 + i];
    kvt[(size_t)bh * 5120 + i] = f2bf(s);
  }
}

// ---------------------------------------------------------------- phi_q + out
// block = (ch, h, b); 128 tokens. attno[token][h*64+d] = (phi_q@kv)/(phi_q.k_sum+eps)
__global__ __launch_bounds__(256) void phiq_out(const unsigned short* __restrict__ qkv,
                                                const unsigned short* __restrict__ RFt,
                                                const unsigned short* __restrict__ kvt,
                                                unsigned short* __restrict__ attno) {
  __shared__ unsigned short RFl[2 * 64 * 32];  // [p][r][32]
  __shared__ unsigned short Ql[2 * 128 * 32];  // [p][n][32]
  __shared__ unsigned short phl[128 * 72];     // [n][r] (+pad)
  __shared__ unsigned short kvl[80 * 72];      // [d][r] (+pad), row 64 = k_sum
  const int t = threadIdx.x, w = t >> 6, lane = t & 63;
  const int ch = blockIdx.x, h = blockIdx.y, b = blockIdx.z;
  const int fr = lane & 15, kg = (lane >> 4) * 8;
  const int bh = b * 16 + h;
  const size_t rowbase = (size_t)(b * 4096 + ch * 128);

#pragma unroll
  for (int i = 0; i < 2; ++i) {
    int unit = i * 256 + w * 64 + lane;
    int p = unit >> 8, rem = unit & 255;
    int r = rem >> 2, cg = (rem & 3) * 8;
    gl_lds16(RFt + ((h * 64 + r) * 64 + p * 32 + cg), &RFl[(i * 256 + w * 64) * 8]);
  }
#pragma unroll
  for (int i = 0; i < 4; ++i) {
    int unit = i * 256 + w * 64 + lane;
    int p = unit >> 9, rem = unit & 511;
    int n = rem >> 2, cg = (rem & 3) * 8;
    gl_lds16(qkv + (rowbase + n) * 3072 + h * 64 + p * 32 + cg,
             &Ql[(i * 256 + w * 64) * 8]);
  }
  for (int i = t; i < 640; i += 256) {  // kvt -> kvl (pad 64->72)
    int row = i >> 3, cg = (i & 7) * 8;
    *(i4v*)&kvl[row * 72 + cg] = *(const i4v*)&kvt[(size_t)bh * 5120 + row * 64 + cg];
  }
  __syncthreads();
  f4v pacc[2][4] = {};
#pragma unroll
  for (int p = 0; p < 2; ++p) {
    s8v qa[2], rb[4];
#pragma unroll
    for (int m = 0; m < 2; ++m)
      qa[m] = *(const s8v*)&Ql[p * 4096 + (w * 32 + m * 16 + fr) * 32 + kg];
#pragma unroll
    for (int rf = 0; rf < 4; ++rf)
      rb[rf] = *(const s8v*)&RFl[p * 2048 + (rf * 16 + fr) * 32 + kg];
#pragma unroll
    for (int m = 0; m < 2; ++m)
#pragma unroll
      for (int rf = 0; rf < 4; ++rf)
        pacc[m][rf] = MFMA16(qa[m], rb[rf], pacc[m][rf]);
  }
#pragma unroll
  for (int m = 0; m < 2; ++m)
#pragma unroll
    for (int rf = 0; rf < 4; ++rf) {
      int r = rf * 16 + fr;
      int nb = w * 32 + m * 16 + (lane >> 4) * 4;
#pragma unroll
      for (int g = 0; g < 4; ++g)
        phl[(nb + g) * 72 + r] = f2bf(fmaxf(pacc[m][rf][g], 0.0f));
    }
  __syncthreads();
  f4v acc[2][5] = {};
#pragma unroll
  for (int kst = 0; kst < 2; ++kst) {
    s8v pa[2], kb[5];
#pragma unroll
    for (int m = 0; m < 2; ++m)
      pa[m] = *(const s8v*)&phl[(w * 32 + m * 16 + fr) * 72 + kst * 32 + kg];
#pragma unroll
    for (int f = 0; f < 5; ++f)
      kb[f] = *(const s8v*)&kvl[(f * 16 + fr) * 72 + kst * 32 + kg];
#pragma unroll
    for (int m = 0; m < 2; ++m)
#pragma unroll
      for (int f = 0; f < 5; ++f) acc[m][f] = MFMA16(pa[m], kb[f], acc[m][f]);
  }
#pragma unroll
  for (int m = 0; m < 2; ++m)
#pragma unroll
    for (int g = 0; g < 4; ++g) {
      float nrm = __shfl(acc[m][4][g], lane & 48) + 1e-6f;  // col 64 = phi_q.k_sum
      int n = w * 32 + m * 16 + (lane >> 4) * 4 + g;
      size_t orow = rowbase + n;
#pragma unroll
      for (int f = 0; f < 4; ++f)
        attno[orow * 1024 + h * 64 + f * 16 + fr] = f2bf(acc[m][f][g] / nrm);
    }
}

// ---------------------------------------------------------------- launch
extern "C" void kernel_launch(void* const* d_in, const int* in_sizes, int n_in,
                              void* d_out, int out_size, void* d_ws, size_t ws_size,
                              hipStream_t stream) {
  const float* x = (const float*)d_in[0];      // [4,4096,1024]
  const float* W_qkv = (const float*)d_in[1];  // [1024,3072]
  const float* RF = (const float*)d_in[2];     // [16,64,64]
  const float* W_out = (const float*)d_in[3];  // [1024,1024]
  const float* b_out = (const float*)d_in[4];  // [1024]
  float* out = (float*)d_out;                  // [4,4096,1024]

  char* ws = (char*)d_ws;
  size_t off = 0;
  auto alloc = [&](size_t bytes) -> void* {
    void* p = ws + off;
    off += (bytes + 255) & ~(size_t)255;
    return p;
  };
  unsigned short* xb = (unsigned short*)alloc(16384ull * 1024 * 2);
  unsigned short* wqkvt = (unsigned short*)alloc(3072ull * 1024 * 2);
  unsigned short* woutt = (unsigned short*)alloc(1024ull * 1024 * 2);
  unsigned short* rft = (unsigned short*)alloc(16ull * 64 * 64 * 2);
  unsigned short* qkv = (unsigned short*)alloc(16384ull * 3072 * 2);
  float* kvpart = (float*)alloc(64ull * 8 * 80 * 64 * 4);
  unsigned short* kvt = (unsigned short*)alloc(64ull * 80 * 64 * 2);
  unsigned short* attno = (unsigned short*)alloc(16384ull * 1024 * 2);

  // fused prep: cvt (16384 blocks) + W_qkv^T (3072) + W_out^T (1024) + RF^T (64)
  prep_all<<<20544, 256, 0, stream>>>(x, xb, W_qkv, wqkvt, W_out, woutt, RF, rft);

  // qkv = xb @ wqkvt^T : M=16384 (64 tiles) x N=3072 (12 tiles), grid 768
  gemm256<0><<<768, 512, 0, stream>>>(xb, wqkvt, qkv, nullptr, 3072, 1024, 12, 96);
  phik_kv<<<dim3(8, 16, 4), 256, 0, stream>>>(qkv, rft, kvpart);
  kv_reduce<<<64, 256, 0, stream>>>(kvpart, kvt);
  phiq_out<<<dim3(32, 16, 4), 256, 0, stream>>>(qkv, rft, kvt, attno);
  // out = attno @ woutt^T + b : M=16384 x N=1024 (4 tiles), grid 256
  gemm256<1><<<256, 512, 0, stream>>>(attno, woutt, out, b_out, 1024, 1024, 4, 32);
}